// Round 9
// baseline (550.843 us; speedup 1.0000x reference)
//
#include <hip/hip_runtime.h>

// ---------------------------------------------------------------------------
// CustomAttention: cosine-sim MHA.  N=1024 seq, B=4 batch, C=1024, H=16, hd=64
// R14: persistent mega-kernel.  Dispatch-sum audit shows ~60-70us of the 202us
//      total is NOT in any kernel (proj 42.7 + flash ~38 + cvt ~20 + out ~30
//      = ~131) -- inter-kernel boundary cost (drain + launch x3).  All 4
//      phases fused into ONE kernel with device-scope grid barriers.
//      Grid 1024x256, launch_bounds(256,4), 32KB shared -> exactly 4
//      blocks/CU, 1024 = 256x4 all co-resident (pigeonhole) -> software
//      barrier safe.  Barrier: monotonic u64 counter in __device__ global
//      (loader-zeroed, floor-read epoch, no resets, replay-safe).
//      Phase geometry = measured best: cvt grid-strided, proj R5-exact
//      (blocks 0-767), flash R12-exact (all 1024), out R5-exact (0-511).
//      Revert path: R12 4-kernel config (202.0us).
// ---------------------------------------------------------------------------

typedef _Float16 f16x8 __attribute__((ext_vector_type(8)));
typedef __fp16   h16x2 __attribute__((ext_vector_type(2)));
typedef float    f32x4 __attribute__((ext_vector_type(4)));

#define LOG2E 1.4426950408889634f
#define LOGMAX 4.6051702f   // log(100)

#define GLOAD16(g, l) \
    __builtin_amdgcn_global_load_lds((__attribute__((address_space(1))) void*)(g), \
                                     (__attribute__((address_space(3))) void*)(l), 16, 0, 0)

__device__ __forceinline__ unsigned short f2h(float x) {
    union { _Float16 h; unsigned short u; } cv;
    cv.h = (_Float16)x;
    return cv.u;
}

// Monotonic grid-barrier counter.  .bss -> zeroed at module load; never reset.
// Each replay adds exactly 3*1024, so every launch starts at a multiple of
// 3072 and blocks recover the epoch with a floor-read (<=1023 arrivals can
// precede the last block's read, so the floor is exact for every block).
__device__ unsigned long long g_cnt;

__device__ __forceinline__ void grid_bar(unsigned long long target) {
    __syncthreads();                       // all waves of this block done
    if (threadIdx.x == 0) {
        __threadfence();                   // release: publish our stores
        atomicAdd(&g_cnt, 1ull);
        long long guard = 0;
        while (__hip_atomic_load(&g_cnt, __ATOMIC_RELAXED, __HIP_MEMORY_SCOPE_AGENT) < target) {
            __builtin_amdgcn_s_sleep(2);
            if (++guard > (1ll << 24)) break;   // safety valve vs. infinite hang
        }
        __threadfence();                   // acquire: see others' stores
    }
    __syncthreads();
}

__global__ __launch_bounds__(256, 4) void mega(
    const float* __restrict__ q, const float* __restrict__ k,
    const float* __restrict__ v, const float* __restrict__ w,
    const float* __restrict__ ow, const float* __restrict__ ipb,
    const float* __restrict__ lsc, const float* __restrict__ ob,
    unsigned short* __restrict__ qbf, unsigned short* __restrict__ kbf,
    unsigned short* __restrict__ vbf, unsigned short* __restrict__ wbf,
    unsigned short* __restrict__ owbf,
    unsigned short* __restrict__ qn, unsigned short* __restrict__ kn,
    unsigned short* __restrict__ vT, unsigned short* __restrict__ xb,
    float* __restrict__ outp)
{
    __shared__ __align__(16) unsigned short smem[16384];   // 32 KB, reused per phase
    const int tid = threadIdx.x;
    const int bid = blockIdx.x;
    const int lane = tid & 63, wave = tid >> 6;
    const int lr = lane & 15, lq = lane >> 4;

    unsigned long long base = 0;
    if (tid == 0)
        base = (__hip_atomic_load(&g_cnt, __ATOMIC_RELAXED, __HIP_MEMORY_SCOPE_AGENT) / 3072ull) * 3072ull;

    // ================= phase 0: fp32 -> fp16 convert (grid-strided) =========
    for (int vb = bid; vb < 16384; vb += 1024) {
        const float* src; unsigned short* dst; int idx;
        if      (vb < 4096)  { src = q;  dst = qbf;  idx = vb; }
        else if (vb < 8192)  { src = k;  dst = kbf;  idx = vb - 4096; }
        else if (vb < 12288) { src = v;  dst = vbf;  idx = vb - 8192; }
        else if (vb < 15360) { src = w;  dst = wbf;  idx = vb - 12288; }
        else                 { src = ow; dst = owbf; idx = vb - 15360; }
        int i = idx * 256 + tid;
        float4 val = ((const float4*)src)[i];
        ushort4 o;
        o.x = f2h(val.x); o.y = f2h(val.y); o.z = f2h(val.z); o.w = f2h(val.w);
        ((ushort4*)dst)[i] = o;
    }
    grid_bar(base + 1024);

    // ================= phase 1: proj GEMM + l2norm epilogue (R5 exact) ======
    if (bid < 768) {
        int wr = wave >> 1, wc = wave & 1;
        int xcd = bid & 7, s = bid >> 3;
        int xt = s & 7, yy = (s >> 3) & 3, z = s >> 5;
        int m0 = (xcd * 4 + yy) * 128, n0 = xt * 128;

        const unsigned short* A = (z == 0) ? qbf : (z == 1) ? kbf : vbf;
        const unsigned short* W = wbf + (size_t)z * 1048576;

        int rl = lane >> 3;
        int cg = ((lane & 7) ^ rl) << 3;
        const unsigned short* gA = A + (size_t)(m0 + wave * 32 + rl) * 1024 + cg;
        const unsigned short* gB = W + (size_t)(n0 + wave * 32 + rl) * 1024 + cg;
        unsigned short* lA = &smem[wave * 2048];
        unsigned short* lB = &smem[8192 + wave * 2048];

        int swz = lr & 7;
        int c0 = (lq ^ swz) << 3;
        int c1 = ((lq ^ 4) ^ swz) << 3;

        f32x4 acc[4][4];
        for (int i = 0; i < 4; i++) for (int j = 0; j < 4; j++) acc[i][j] = (f32x4){0.f, 0.f, 0.f, 0.f};

        for (int ki = 0; ki < 16; ++ki) {
            for (int j = 0; j < 4; ++j) {
                GLOAD16(gA + ki * 64 + j * 8192, lA + j * 512);
                GLOAD16(gB + ki * 64 + j * 8192, lB + j * 512);
            }
            __syncthreads();
            for (int kc = 0; kc < 2; ++kc) {
                int co = kc ? c1 : c0;
                f16x8 af[4], bfr[4];
                for (int mi = 0; mi < 4; ++mi) af[mi]  = *(const f16x8*)&smem[(wr * 64 + mi * 16 + lr) * 64 + co];
                for (int ni = 0; ni < 4; ++ni) bfr[ni] = *(const f16x8*)&smem[8192 + (wc * 64 + ni * 16 + lr) * 64 + co];
                for (int mi = 0; mi < 4; ++mi)
                    for (int ni = 0; ni < 4; ++ni)
                        acc[mi][ni] = __builtin_amdgcn_mfma_f32_16x16x32_f16(af[mi], bfr[ni], acc[mi][ni], 0, 0, 0);
            }
            __syncthreads();
        }

        int h = (n0 >> 6) + wc;
        float bv[4];
        for (int ni = 0; ni < 4; ++ni) bv[ni] = ipb[z * 1024 + n0 + wc * 64 + ni * 16 + lr];
        for (int mi = 0; mi < 4; ++mi)
            for (int ni = 0; ni < 4; ++ni)
                for (int r = 0; r < 4; ++r) acc[mi][ni][r] += bv[ni];

        float lsfac = __expf(fminf(lsc[h], LOGMAX)) * LOG2E;

        for (int mi = 0; mi < 4; ++mi)
            for (int r = 0; r < 4; ++r) {
                int row = m0 + wr * 64 + mi * 16 + lq * 4 + r;   // m = n*4 + b
                int n = row >> 2, b = row & 3;
                int bh = b * 16 + h;
                if (z < 2) {
                    float ss = 0.f;
                    for (int ni = 0; ni < 4; ++ni) ss += acc[mi][ni][r] * acc[mi][ni][r];
                    for (int off = 1; off < 16; off <<= 1) ss += __shfl_xor(ss, off);
                    float scale = 1.0f / fmaxf(sqrtf(ss), 1e-12f);
                    if (z == 0) scale *= lsfac;
                    unsigned short* dst = (z == 0) ? qn : kn;
                    for (int ni = 0; ni < 4; ++ni)
                        dst[(size_t)bh * 65536 + (size_t)n * 64 + ni * 16 + lr] = f2h(acc[mi][ni][r] * scale);
                } else {
                    for (int ni = 0; ni < 4; ++ni)
                        vT[(size_t)bh * 65536 + (size_t)(ni * 16 + lr) * 1024 + n] = f2h(acc[mi][ni][r]);
                }
            }
    }
    grid_bar(base + 2048);

    // ================= phase 2: flash attention (R12 exact, all 1024) =======
    {
        int xcd = bid & 7, s2 = bid >> 3;            // s2 in [0,128)
        int qt = s2 & 15, bh = xcd * 8 + (s2 >> 4);
        int q0 = qt * 64;

        float offv = __expf(fminf(lsc[bh & 15], LOGMAX)) * LOG2E - 12.0f;
        f32x4 initv = (f32x4){-offv, -offv, -offv, -offv};

        f16x8 qf[2];
        for (int kc = 0; kc < 2; ++kc)
            qf[kc] = *(const f16x8*)(qn + (size_t)bh * 65536 +
                          (size_t)(q0 + wave * 16 + lr) * 64 + kc * 32 + lq * 8);

        int rl = lane >> 3;
        int cg = ((lane & 7) ^ rl) << 3;
        const unsigned short* gK = kn + (size_t)bh * 65536 + (size_t)(wave * 16 + rl) * 64 + cg;
        const unsigned short* gV = vT + (size_t)bh * 65536 + (size_t)(wave * 16 + rl) * 1024 + cg;
        unsigned short* lK = &smem[wave * 1024];
        unsigned short* lV = &smem[4096 + wave * 1024];
        unsigned short* Pl = &smem[8192];            // [4][16][72]
        int swz = lr & 7;
        int c0 = (lq ^ swz) << 3;
        int c1 = ((lq ^ 4) ^ swz) << 3;

        f32x4 o4[4];
        for (int i = 0; i < 4; i++) o4[i] = (f32x4){0.f, 0.f, 0.f, 0.f};
        float lsum = 0.f;

        for (int kt = 0; kt < 16; ++kt) {
            for (int j = 0; j < 2; ++j) {
                GLOAD16(gK + kt * 4096 + j * 512,  lK + j * 512);
                GLOAD16(gV + kt * 64  + j * 8192,  lV + j * 512);
            }
            __syncthreads();

            f32x4 sc[4];
            __builtin_amdgcn_s_setprio(1);
            for (int ct = 0; ct < 4; ++ct)
                for (int kc = 0; kc < 2; ++kc) {
                    f16x8 kf = *(const f16x8*)&smem[(ct * 16 + lr) * 64 + (kc ? c1 : c0)];
                    sc[ct] = __builtin_amdgcn_mfma_f32_16x16x32_f16(
                        kf, qf[kc], kc == 0 ? initv : sc[ct], 0, 0, 0);
                }
            __builtin_amdgcn_s_setprio(0);

            for (int ct = 0; ct < 4; ++ct) {
                float p0 = __builtin_amdgcn_exp2f(sc[ct][0]);
                float p1 = __builtin_amdgcn_exp2f(sc[ct][1]);
                float p2 = __builtin_amdgcn_exp2f(sc[ct][2]);
                float p3 = __builtin_amdgcn_exp2f(sc[ct][3]);
                lsum += (p0 + p1) + (p2 + p3);
                union { h16x2 h[2]; ushort4 u; } pw;
                pw.h[0] = __builtin_amdgcn_cvt_pkrtz(p0, p1);
                pw.h[1] = __builtin_amdgcn_cvt_pkrtz(p2, p3);
                *(ushort4*)&Pl[(wave * 16 + lr) * 72 + ct * 16 + lq * 4] = pw.u;
            }

            f16x8 pf[2];
            for (int kc = 0; kc < 2; ++kc)
                pf[kc] = *(const f16x8*)&Pl[(wave * 16 + lr) * 72 + kc * 32 + lq * 8];
            __builtin_amdgcn_s_setprio(1);
            for (int nt = 0; nt < 4; ++nt)
                for (int kc = 0; kc < 2; ++kc) {
                    f16x8 vf = *(const f16x8*)&smem[4096 + (nt * 16 + lr) * 64 + (kc ? c1 : c0)];
                    o4[nt] = __builtin_amdgcn_mfma_f32_16x16x32_f16(vf, pf[kc], o4[nt], 0, 0, 0);
                }
            __builtin_amdgcn_s_setprio(0);
            __syncthreads();
        }

        int b = bh >> 4, h = bh & 15;
        float ls = lsum;
        ls += __shfl_xor(ls, 16);
        ls += __shfl_xor(ls, 32);
        float inv = 1.0f / ls;
        size_t m = (size_t)(q0 + wave * 16 + lr) * 4 + b;
        for (int nt = 0; nt < 4; ++nt) {
            ushort4 wv;
            wv.x = f2h(o4[nt][0] * inv); wv.y = f2h(o4[nt][1] * inv);
            wv.z = f2h(o4[nt][2] * inv); wv.w = f2h(o4[nt][3] * inv);
            *(ushort4*)(xb + m * 1024 + h * 64 + nt * 16 + lq * 4) = wv;
        }
    }
    grid_bar(base + 3072);

    // ================= phase 3: output GEMM (R5 exact, 512 active) ==========
    if (bid < 512) {
        int xcd = bid & 7, s3 = bid >> 3;
        int xt = s3 & 15, yy = s3 >> 4;
        int m0 = (xcd * 4 + yy) * 128, n0 = xt * 64;

        int rl = lane >> 3;
        int cg = ((lane & 7) ^ rl) << 3;
        const unsigned short* gA = xb   + (size_t)(m0 + wave * 32 + rl) * 1024 + cg;
        const unsigned short* gB = owbf + (size_t)(n0 + wave * 16 + rl) * 1024 + cg;
        unsigned short* lA = &smem[wave * 2048];
        unsigned short* lB = &smem[8192 + wave * 1024];
        int swz = lr & 7;
        int c0 = (lq ^ swz) << 3;
        int c1 = ((lq ^ 4) ^ swz) << 3;

        f32x4 acc[2][4];
        for (int i = 0; i < 2; i++) for (int j = 0; j < 4; j++) acc[i][j] = (f32x4){0.f, 0.f, 0.f, 0.f};

        for (int ki = 0; ki < 16; ++ki) {
            for (int j = 0; j < 4; ++j)
                GLOAD16(gA + ki * 64 + j * 8192, lA + j * 512);
            for (int j = 0; j < 2; ++j)
                GLOAD16(gB + ki * 64 + j * 8192, lB + j * 512);
            __syncthreads();
            for (int kc = 0; kc < 2; ++kc) {
                int co = kc ? c1 : c0;
                f16x8 af[2], bfr[4];
                for (int mi = 0; mi < 2; ++mi) af[mi]  = *(const f16x8*)&smem[(wave * 32 + mi * 16 + lr) * 64 + co];
                for (int ni = 0; ni < 4; ++ni) bfr[ni] = *(const f16x8*)&smem[8192 + (ni * 16 + lr) * 64 + co];
                for (int mi = 0; mi < 2; ++mi)
                    for (int ni = 0; ni < 4; ++ni)
                        acc[mi][ni] = __builtin_amdgcn_mfma_f32_16x16x32_f16(af[mi], bfr[ni], acc[mi][ni], 0, 0, 0);
            }
            __syncthreads();
        }
        for (int mi = 0; mi < 2; ++mi)
            for (int ni = 0; ni < 4; ++ni)
                for (int r = 0; r < 4; ++r) {
                    int row = m0 + wave * 32 + mi * 16 + lq * 4 + r;
                    int col = n0 + ni * 16 + lr;
                    outp[(size_t)row * 1024 + col] = acc[mi][ni][r] + ob[col];
                }
    }
}

extern "C" void kernel_launch(void* const* d_in, const int* in_sizes, int n_in,
                              void* d_out, int out_size, void* d_ws, size_t ws_size,
                              hipStream_t stream) {
    const float* query = (const float*)d_in[0];
    const float* key   = (const float*)d_in[1];
    const float* value = (const float*)d_in[2];
    const float* ipw   = (const float*)d_in[3];
    const float* ipb   = (const float*)d_in[4];
    const float* lsc   = (const float*)d_in[5];
    const float* ow    = (const float*)d_in[6];
    const float* ob    = (const float*)d_in[7];
    float* outp = (float*)d_out;

    char* ws = (char*)d_ws;
    unsigned short* qbf  = (unsigned short*)(ws);               // 8 MB fp16 query
    unsigned short* kbf  = (unsigned short*)(ws + 8388608);     // 8 MB
    unsigned short* vbf  = (unsigned short*)(ws + 16777216);    // 8 MB
    unsigned short* wbf  = (unsigned short*)(ws + 25165824);    // 6 MB in_proj_w
    unsigned short* owbf = (unsigned short*)(ws + 31457280);    // 2 MB out_w
    unsigned short* qn   = (unsigned short*)(ws + 33554432);    // 8 MB normalized q (bh,n,d)
    unsigned short* kn   = (unsigned short*)(ws + 41943040);    // 8 MB normalized k
    unsigned short* vT   = (unsigned short*)(ws + 50331648);    // 8 MB v^T (bh,d,n)
    unsigned short* xbuf = (unsigned short*)(ws + 58720256);    // 8 MB attn out (m, c)

    mega<<<1024, 256, 0, stream>>>(query, key, value, ipw, ow, ipb, lsc, ob,
                                   qbf, kbf, vbf, wbf, owbf,
                                   qn, kn, vT, xbuf, outp);
}